// Round 3
// baseline (334.760 us; speedup 1.0000x reference)
//
#include <hip/hip_runtime.h>
#include <cstdint>
#include <cstddef>

#define N_NODES 50000
#define N_EDGES 300000
#define DIM     256
#define KTOT    768   // concatenated K: [agg*norm | h | prev_h]
#define N_RELS  500
#define XW      768   // Xcat row width: [agg | h | prev_h] bf16

#define SCAN_BLK  256
#define SCAN_NBLK ((N_NODES + SCAN_BLK - 1) / SCAN_BLK)   // 196

#define CONV_ELEMS ((2 * N_NODES + N_RELS) * DIM)
#define CONV_BLKS  ((CONV_ELEMS / 8 + 255) / 256)
#define HIST_BLKS  ((N_EDGES + 255) / 256)

typedef unsigned short u16;
typedef __attribute__((ext_vector_type(8))) short short8v;   // 8 bf16 = 4 VGPRs (MFMA A/B frag)
typedef __attribute__((ext_vector_type(4))) float float4v;   // MFMA C/D frag

static __device__ __forceinline__ u16 f2bf(float f) {
    union { float f; unsigned u; } v; v.f = f;
    unsigned u = v.u;
    unsigned r = u + 0x7FFFu + ((u >> 16) & 1u);  // RNE
    return (u16)(r >> 16);
}
static __device__ __forceinline__ float bf2f(u16 b) {
    union { unsigned u; float f; } v; v.u = ((unsigned)b) << 16; return v.f;
}

// async global->LDS, 16B per lane, LDS dest = wave-uniform base + lane*16 (linear)
static __device__ __forceinline__ void gld16(const void* g, u16* l) {
    __builtin_amdgcn_global_load_lds(
        (const __attribute__((address_space(1))) unsigned int*)g,
        (__attribute__((address_space(3))) unsigned int*)l,
        16, 0, 0);
}

// ---------------- K1 (fused): conv(h, prev_h, emb -> bf16) + Wt build + in-deg hist ------
__global__ void prep_kernel(const float* __restrict__ h, const float* __restrict__ prev_h,
                            const float* __restrict__ emb,
                            const float* __restrict__ Wn, const float* __restrict__ Wl,
                            const float* __restrict__ Wsc, const int* __restrict__ dstv,
                            u16* __restrict__ Xcat, u16* __restrict__ embb,
                            u16* __restrict__ Wt, int* __restrict__ deg) {
    int b = blockIdx.x;
    if (b < CONV_BLKS) {
        int i = b * 256 + threadIdx.x;
        int e0 = i * 8;
        if (e0 >= CONV_ELEMS) return;
        const float* s; u16* d;
        if (e0 < N_NODES * DIM) {
            int n = e0 >> 8, c = e0 & 255;
            s = h + e0; d = Xcat + (size_t)n * XW + 256 + c;          // h-slice
        } else if (e0 < 2 * N_NODES * DIM) {
            int o = e0 - N_NODES * DIM;
            int n = o >> 8, c = o & 255;
            s = prev_h + o; d = Xcat + (size_t)n * XW + 512 + c;      // prev-slice
        } else {
            int o = e0 - 2 * N_NODES * DIM;
            s = emb + o; d = embb + o;
        }
        float4 a = *(const float4*)(s);
        float4 c2 = *(const float4*)(s + 4);
        u16 o8[8] = { f2bf(a.x), f2bf(a.y), f2bf(a.z), f2bf(a.w),
                      f2bf(c2.x), f2bf(c2.y), f2bf(c2.z), f2bf(c2.w) };
        *(uint4*)d = *(const uint4*)o8;
    } else if (b < CONV_BLKS + KTOT) {
        int k = b - CONV_BLKS;          // 0..767
        int dd = threadIdx.x;           // 0..255
        const float* W = (k < 256) ? Wn : ((k < 512) ? Wl : Wsc);
        Wt[(size_t)dd * KTOT + k] = f2bf(W[(k & 255) * DIM + dd]);
    } else {
        int e = (b - CONV_BLKS - KTOT) * 256 + threadIdx.x;
        if (e < N_EDGES) atomicAdd(&deg[dstv[e]], 1);
    }
}

// ---------------- K4a: per-block scan of deg ----------------
__global__ void scanA_kernel(const int* __restrict__ deg, int* __restrict__ excl_local,
                             int* __restrict__ block_sum) {
    __shared__ int sdata[SCAN_BLK];
    int t = threadIdx.x, i = blockIdx.x * SCAN_BLK + t;
    int v = (i < N_NODES) ? deg[i] : 0;
    sdata[t] = v;
    __syncthreads();
    for (int off = 1; off < SCAN_BLK; off <<= 1) {
        int u = (t >= off) ? sdata[t - off] : 0;
        __syncthreads();
        sdata[t] += u;
        __syncthreads();
    }
    if (i < N_NODES) excl_local[i] = sdata[t] - v;
    if (t == SCAN_BLK - 1) block_sum[blockIdx.x] = sdata[t];
}

// ---------------- K4b: scan 196 block sums (1 block) ----------------
__global__ void scanB_kernel(const int* __restrict__ block_sum, int* __restrict__ block_base,
                             int* __restrict__ offsets) {
    __shared__ int sdata[SCAN_NBLK];
    int t = threadIdx.x;
    int v = (t < SCAN_NBLK) ? block_sum[t] : 0;
    if (t < SCAN_NBLK) sdata[t] = v;
    __syncthreads();
    for (int off = 1; off < SCAN_NBLK; off <<= 1) {
        int u = (t >= off && t < SCAN_NBLK) ? sdata[t - off] : 0;
        __syncthreads();
        if (t < SCAN_NBLK) sdata[t] += u;
        __syncthreads();
    }
    if (t < SCAN_NBLK) block_base[t] = sdata[t] - v;
    if (t == SCAN_NBLK - 1) offsets[N_NODES] = sdata[t];
}

// ---------------- K4c: combine -> offsets, cursor ----------------
__global__ void scanC_kernel(const int* __restrict__ excl_local, const int* __restrict__ block_base,
                             int* __restrict__ offsets, int* __restrict__ cursor) {
    int i = blockIdx.x * SCAN_BLK + threadIdx.x;
    if (i < N_NODES) {
        int e = block_base[blockIdx.x] + excl_local[i];
        offsets[i] = e; cursor[i] = e;
    }
}

// ---------------- K5: scatter edges into CSR slots (packed src*500+et) ----------------
__global__ void scatter_kernel(const int* __restrict__ src, const int* __restrict__ dstv,
                               const int* __restrict__ et, int* __restrict__ cursor,
                               unsigned* __restrict__ esee) {
    int e = blockIdx.x * 256 + threadIdx.x;
    if (e >= N_EDGES) return;
    int d = dstv[e];
    int pos = atomicAdd(&cursor[d], 1);
    esee[pos] = (unsigned)src[e] * N_RELS + (unsigned)et[e];
}

// ---------------- K6: wave-per-node gather-reduce -> Xcat[:,0:256] ----------------
// 4-edge unroll for memory-level parallelism (latency-bound gather).
__global__ void agg_kernel(u16* __restrict__ Xcat, const u16* __restrict__ embb,
                           const float* __restrict__ norm, const int* __restrict__ offsets,
                           const unsigned* __restrict__ esee,
                           int* __restrict__ wl_count, int* __restrict__ wl) {
    int wave = (blockIdx.x * 256 + threadIdx.x) >> 6;
    int lane = threadIdx.x & 63;
    if (wave >= N_NODES) return;
    int n = wave;
    int s0 = offsets[n], s1 = offsets[n + 1];
    int c4 = lane * 4;
    float4 acc = make_float4(0.f, 0.f, 0.f, 0.f);
    int e = s0;
    for (; e + 3 < s1; e += 4) {
        unsigned v0 = esee[e], v1 = esee[e + 1], v2 = esee[e + 2], v3 = esee[e + 3];
        unsigned sa = v0 / N_RELS, ta = v0 - sa * N_RELS;
        unsigned sb = v1 / N_RELS, tb = v1 - sb * N_RELS;
        unsigned sc = v2 / N_RELS, tc = v2 - sc * N_RELS;
        unsigned sd = v3 / N_RELS, td = v3 - sd * N_RELS;
        ushort4 ha = *(const ushort4*)(Xcat + (size_t)sa * XW + 256 + c4);
        ushort4 ea = *(const ushort4*)(embb + (size_t)ta * DIM + c4);
        ushort4 hb = *(const ushort4*)(Xcat + (size_t)sb * XW + 256 + c4);
        ushort4 eb = *(const ushort4*)(embb + (size_t)tb * DIM + c4);
        ushort4 hc = *(const ushort4*)(Xcat + (size_t)sc * XW + 256 + c4);
        ushort4 ec = *(const ushort4*)(embb + (size_t)tc * DIM + c4);
        ushort4 hd = *(const ushort4*)(Xcat + (size_t)sd * XW + 256 + c4);
        ushort4 ed = *(const ushort4*)(embb + (size_t)td * DIM + c4);
        acc.x += (bf2f(ha.x) + bf2f(ea.x)) + (bf2f(hb.x) + bf2f(eb.x))
               + (bf2f(hc.x) + bf2f(ec.x)) + (bf2f(hd.x) + bf2f(ed.x));
        acc.y += (bf2f(ha.y) + bf2f(ea.y)) + (bf2f(hb.y) + bf2f(eb.y))
               + (bf2f(hc.y) + bf2f(ec.y)) + (bf2f(hd.y) + bf2f(ed.y));
        acc.z += (bf2f(ha.z) + bf2f(ea.z)) + (bf2f(hb.z) + bf2f(eb.z))
               + (bf2f(hc.z) + bf2f(ec.z)) + (bf2f(hd.z) + bf2f(ed.z));
        acc.w += (bf2f(ha.w) + bf2f(ea.w)) + (bf2f(hb.w) + bf2f(eb.w))
               + (bf2f(hc.w) + bf2f(ec.w)) + (bf2f(hd.w) + bf2f(ed.w));
    }
    for (; e < s1; e++) {
        unsigned v = esee[e];
        unsigned s = v / N_RELS;
        unsigned t = v - s * N_RELS;
        ushort4 hv = *(const ushort4*)(Xcat + (size_t)s * XW + 256 + c4);
        ushort4 ev = *(const ushort4*)(embb + (size_t)t * DIM + c4);
        acc.x += bf2f(hv.x) + bf2f(ev.x);
        acc.y += bf2f(hv.y) + bf2f(ev.y);
        acc.z += bf2f(hv.z) + bf2f(ev.z);
        acc.w += bf2f(hv.w) + bf2f(ev.w);
    }
    float nr = norm[n];
    u16 o[4] = { f2bf(acc.x * nr), f2bf(acc.y * nr), f2bf(acc.z * nr), f2bf(acc.w * nr) };
    *(ushort4*)(Xcat + (size_t)n * XW + c4) = *(const ushort4*)o;
    if (lane == 0 && s1 == s0) { int idx = atomicAdd(wl_count, 1); wl[idx] = n; }
}

// ---------------- K7: fused MFMA GEMM, T14 reg-staged-A pipeline ----------------
// Block: 256 thr = 4 waves. Tile: 64 nodes x 256 cols (wave w: cols [w*64,+64)). BK=64.
// A (Xcat rows, HBM-latency) is staged via REGISTERS (issue head of kt, ds_write tail of
// kt) so the only wait on it is the compiler's precise counted vmcnt before the ds_write —
// immune to LDS-alias analysis. B (Wt, L2-resident) stays global_load_lds, issued at head
// of kt for tile kt+1 (full compute phase to land). Tail __syncthreads drains free:
// everything outstanding was issued a full phase earlier (except fresh B, <=L2 latency).
// Swizzle: source col pre-XOR (lc8^lr), linear LDS dest, read col XOR (m16&7)<<3.
// LDS: A 2x8KB @u16[0/4096], B 2x32KB @u16[8192/24576] = 80KB -> 2 blocks/CU.
__launch_bounds__(256, 2)
__global__ void gemm_kernel(const u16* __restrict__ Xcat, const u16* __restrict__ Wt,
                            const float* __restrict__ prev_h, const float* __restrict__ bias,
                            float* __restrict__ out) {
    __shared__ __align__(16) u16 lds[40960];   // 81920 B
    int tid  = threadIdx.x;
    int wave = tid >> 6, lane = tid & 63, q = lane >> 4, m16 = lane & 15;
    int wn = wave * 64;
    int m0 = blockIdx.x * 64;
    int lr = lane >> 3, lc8 = lane & 7;
    int scol = (lc8 ^ lr) << 3;                // pre-swizzled source col (u16 units)

    int ar0 = wave * 16 + lr, ar1 = ar0 + 8;
    int ga0 = (m0 + ar0 < N_NODES) ? (m0 + ar0) : (N_NODES - 1);
    int ga1 = (m0 + ar1 < N_NODES) ? (m0 + ar1) : (N_NODES - 1);
    const u16* sA0 = Xcat + (size_t)ga0 * XW + scol;
    const u16* sA1 = Xcat + (size_t)ga1 * XW + scol;
    const u16* sB  = Wt + (size_t)(wave * 64 + lr) * KTOT + scol;
    int ldsB_w = 8192 + wave * 64 * 64;        // wave-uniform B base (+buf*16384, +j*512)
    // per-thread A ds_write offsets (identical mapping to gld16: base + lane*16B)
    int ldsA_t0 = wave * 16 * 64 + lane * 8;   // chunk 0 (+buf*4096)
    int ldsA_t1 = ldsA_t0 + 512;               // chunk 1

    float4v acc1[4][4], acc2[4][4];
#pragma unroll
    for (int i = 0; i < 4; i++)
#pragma unroll
        for (int j = 0; j < 4; j++) { acc1[i][j] = (float4v)0.f; acc2[i][j] = (float4v)0.f; }

    uint4 rA[2][2];   // two staging sets, fully static indexing under unroll (rule #20)

    auto loadA = [&](int kt, int s) {
        rA[s][0] = *(const uint4*)(sA0 + kt * 64);
        rA[s][1] = *(const uint4*)(sA1 + kt * 64);
    };
    auto writeA = [&](int buf, int s) {
        *(uint4*)(&lds[buf * 4096 + ldsA_t0]) = rA[s][0];
        *(uint4*)(&lds[buf * 4096 + ldsA_t1]) = rA[s][1];
    };
    auto stageB = [&](int kt, int buf) {
#pragma unroll
        for (int j = 0; j < 8; j++)
            gld16(sB + (size_t)j * 8 * KTOT + kt * 64, &lds[ldsB_w + buf * 16384 + j * 512]);
    };

    // ---- prologue: tile 0 to LDS, A(1) in regs ----
    loadA(0, 0);
    loadA(1, 1);
    stageB(0, 0);
    writeA(0, 0);          // counted wait on A(0) only
    __syncthreads();       // pays one full drain (prologue only)

    int sw = (m16 & 7) << 3;   // read-side swizzle (u16 units)

#pragma unroll
    for (int kt = 0; kt < 12; kt++) {
        int buf = kt & 1, nbuf = buf ^ 1;
        // head: B(kt+1) -> nbuf (full phase to land); A(kt+2) -> regs (full phase in flight)
        if (kt + 1 < 12) stageB(kt + 1, nbuf);
        if (kt + 2 < 12) loadA(kt + 2, kt & 1);

#pragma unroll
        for (int kk = 0; kk < 2; kk++) {
            int ck = (kk * 32 + q * 8) ^ sw;
            short8v af[4], bfr[4];
#pragma unroll
            for (int mi = 0; mi < 4; mi++)
                af[mi] = *(const short8v*)(&lds[buf * 4096 + (mi * 16 + m16) * 64 + ck]);
#pragma unroll
            for (int ni = 0; ni < 4; ni++)
                bfr[ni] = *(const short8v*)(&lds[8192 + buf * 16384 + (wn + ni * 16 + m16) * 64 + ck]);
            if (kt < 8) {
#pragma unroll
                for (int mi = 0; mi < 4; mi++)
#pragma unroll
                    for (int ni = 0; ni < 4; ni++)
                        acc1[mi][ni] = __builtin_amdgcn_mfma_f32_16x16x32_bf16(
                            af[mi], bfr[ni], acc1[mi][ni], 0, 0, 0);
            } else {
#pragma unroll
                for (int mi = 0; mi < 4; mi++)
#pragma unroll
                    for (int ni = 0; ni < 4; ni++)
                        acc2[mi][ni] = __builtin_amdgcn_mfma_f32_16x16x32_bf16(
                            af[mi], bfr[ni], acc2[mi][ni], 0, 0, 0);
            }
        }

        // tail: A(kt+1) regs (loaded a full phase ago) -> nbuf
        if (kt + 1 < 12) writeA(nbuf, (kt + 1) & 1);
        __syncthreads();   // drain is ~free: all outstanding vmem issued a phase earlier
    }

    // epilogue: C/D layout col=lane&15, row=q*4+reg  [measured m89]
#pragma unroll
    for (int mi = 0; mi < 4; mi++) {
#pragma unroll
        for (int ni = 0; ni < 4; ni++) {
            int d = wn + ni * 16 + m16;
            float b = bias[d];
#pragma unroll
            for (int r = 0; r < 4; r++) {
                int node = m0 + mi * 16 + q * 4 + r;
                if (node < N_NODES) {
                    float S  = acc2[mi][ni][r] + b;
                    float sg = 1.f / (1.f + __expf(-S));
                    float ph = prev_h[(size_t)node * DIM + d];
                    float v  = sg * acc1[mi][ni][r] + (1.f - sg) * ph;
                    out[(size_t)node * DIM + d] = fmaxf(v, 0.f);
                }
            }
        }
    }
}

// ---------------- K8: fixup for in_deg==0 nodes (evolve_loop_weight path, exact fp32) --------
__global__ void fixup_kernel(const float* __restrict__ h, const float* __restrict__ prev_h,
                             const float* __restrict__ We, const float* __restrict__ Wsc,
                             const float* __restrict__ bias, const int* __restrict__ wl_count,
                             const int* __restrict__ wl, float* __restrict__ out) {
    __shared__ float ph[DIM], hh[DIM];
    int d = threadIdx.x;
    int cnt = *wl_count;
    for (int i = blockIdx.x; i < cnt; i += gridDim.x) {
        int n = wl[i];
        ph[d] = prev_h[(size_t)n * DIM + d];
        hh[d] = h[(size_t)n * DIM + d];
        __syncthreads();
        float s = 0.f, l = 0.f;
        for (int k = 0; k < DIM; k++) {
            s += ph[k] * Wsc[k * DIM + d];
            l += hh[k] * We[k * DIM + d];
        }
        float sg = 1.f / (1.f + __expf(-(s + bias[d])));
        float v = sg * l + (1.f - sg) * ph[d];
        out[(size_t)n * DIM + d] = fmaxf(v, 0.f);
        __syncthreads();
    }
}

extern "C" void kernel_launch(void* const* d_in, const int* in_sizes, int n_in,
                              void* d_out, int out_size, void* d_ws, size_t ws_size,
                              hipStream_t stream) {
    const float* h      = (const float*)d_in[0];
    const float* prev_h = (const float*)d_in[1];
    const float* emb    = (const float*)d_in[2];
    const float* norm   = (const float*)d_in[3];
    const float* Wn     = (const float*)d_in[4];
    const float* Wl     = (const float*)d_in[5];
    const float* We     = (const float*)d_in[6];
    const float* Wsc    = (const float*)d_in[7];
    const float* bias   = (const float*)d_in[8];
    const int*   src    = (const int*)d_in[9];
    const int*   dstv   = (const int*)d_in[10];
    const int*   et     = (const int*)d_in[11];
    float* out = (float*)d_out;

    char* ws = (char*)d_ws;
    size_t off = 0;
    auto alloc = [&](size_t bytes) -> char* {
        char* p = ws + off; off += (bytes + 255) & ~(size_t)255; return p;
    };
    u16* Xcat    = (u16*)alloc((size_t)N_NODES * XW * 2);   // [agg | h | prev] bf16
    u16* embb    = (u16*)alloc((size_t)N_RELS * DIM * 2);
    u16* Wt      = (u16*)alloc((size_t)DIM * KTOT * 2);
    int* deg     = (int*)alloc((size_t)N_NODES * 4);
    int* wlcnt   = (int*)alloc(16);
    int* wl      = (int*)alloc((size_t)N_NODES * 4);
    int* offsets = (int*)alloc((size_t)(N_NODES + 1) * 4);
    int* cursor  = (int*)alloc((size_t)N_NODES * 4);
    unsigned* esee = (unsigned*)alloc((size_t)N_EDGES * 4);
    int* excl    = (int*)alloc((size_t)N_NODES * 4);
    int* bsum    = (int*)alloc((size_t)SCAN_NBLK * 4);
    int* bbase   = (int*)alloc((size_t)SCAN_NBLK * 4);

    hipMemsetAsync(deg, 0, (size_t)N_NODES * 4, stream);
    hipMemsetAsync(wlcnt, 0, 4, stream);

    prep_kernel<<<CONV_BLKS + KTOT + HIST_BLKS, 256, 0, stream>>>(
        h, prev_h, emb, Wn, Wl, Wsc, dstv, Xcat, embb, Wt, deg);
    scanA_kernel<<<SCAN_NBLK, SCAN_BLK, 0, stream>>>(deg, excl, bsum);
    scanB_kernel<<<1, SCAN_BLK, 0, stream>>>(bsum, bbase, offsets);
    scanC_kernel<<<SCAN_NBLK, SCAN_BLK, 0, stream>>>(excl, bbase, offsets, cursor);
    scatter_kernel<<<(N_EDGES + 255) / 256, 256, 0, stream>>>(src, dstv, et, cursor, esee);
    agg_kernel<<<(N_NODES + 3) / 4, 256, 0, stream>>>(Xcat, embb, norm, offsets, esee, wlcnt, wl);
    gemm_kernel<<<(N_NODES + 63) / 64, 256, 0, stream>>>(Xcat, Wt, prev_h, bias, out);
    fixup_kernel<<<256, 256, 0, stream>>>(h, prev_h, We, Wsc, bias, wlcnt, wl, out);
}

// Round 4
// 312.728 us; speedup vs baseline: 1.0705x; 1.0705x over previous
//
#include <hip/hip_runtime.h>
#include <cstdint>
#include <cstddef>

#define N_NODES 50000
#define N_EDGES 300000
#define DIM     256
#define KTOT    768   // concatenated K: [agg*norm | h | prev_h]
#define N_RELS  500
#define XW      768   // Xcat row width: [agg | h | prev_h] bf16

#define SCAN_BLK  256
#define SCAN_NBLK ((N_NODES + SCAN_BLK - 1) / SCAN_BLK)   // 196

#define CONV_ELEMS ((2 * N_NODES + N_RELS) * DIM)
#define CONV_BLKS  ((CONV_ELEMS / 8 + 255) / 256)
#define HIST_BLKS  ((N_EDGES + 255) / 256)

typedef unsigned short u16;
typedef __attribute__((ext_vector_type(8))) short short8v;   // 8 bf16 = 4 VGPRs (MFMA A/B frag)
typedef __attribute__((ext_vector_type(4))) float float4v;   // MFMA C/D frag

static __device__ __forceinline__ u16 f2bf(float f) {
    union { float f; unsigned u; } v; v.f = f;
    unsigned u = v.u;
    unsigned r = u + 0x7FFFu + ((u >> 16) & 1u);  // RNE
    return (u16)(r >> 16);
}
static __device__ __forceinline__ float bf2f(u16 b) {
    union { unsigned u; float f; } v; v.u = ((unsigned)b) << 16; return v.f;
}

// async global->LDS, 16B per lane, LDS dest = wave-uniform base + lane*16 (linear)
static __device__ __forceinline__ void gld16(const void* g, u16* l) {
    __builtin_amdgcn_global_load_lds(
        (const __attribute__((address_space(1))) unsigned int*)g,
        (__attribute__((address_space(3))) unsigned int*)l,
        16, 0, 0);
}

// ---------------- K1 (fused): conv(h, prev_h, emb -> bf16) + Wt build + in-deg hist ------
__global__ void prep_kernel(const float* __restrict__ h, const float* __restrict__ prev_h,
                            const float* __restrict__ emb,
                            const float* __restrict__ Wn, const float* __restrict__ Wl,
                            const float* __restrict__ Wsc, const int* __restrict__ dstv,
                            u16* __restrict__ Xcat, u16* __restrict__ embb,
                            u16* __restrict__ Wt, int* __restrict__ deg) {
    int b = blockIdx.x;
    if (b < CONV_BLKS) {
        int i = b * 256 + threadIdx.x;
        int e0 = i * 8;
        if (e0 >= CONV_ELEMS) return;
        const float* s; u16* d;
        if (e0 < N_NODES * DIM) {
            int n = e0 >> 8, c = e0 & 255;
            s = h + e0; d = Xcat + (size_t)n * XW + 256 + c;          // h-slice
        } else if (e0 < 2 * N_NODES * DIM) {
            int o = e0 - N_NODES * DIM;
            int n = o >> 8, c = o & 255;
            s = prev_h + o; d = Xcat + (size_t)n * XW + 512 + c;      // prev-slice
        } else {
            int o = e0 - 2 * N_NODES * DIM;
            s = emb + o; d = embb + o;
        }
        float4 a = *(const float4*)(s);
        float4 c2 = *(const float4*)(s + 4);
        u16 o8[8] = { f2bf(a.x), f2bf(a.y), f2bf(a.z), f2bf(a.w),
                      f2bf(c2.x), f2bf(c2.y), f2bf(c2.z), f2bf(c2.w) };
        *(uint4*)d = *(const uint4*)o8;
    } else if (b < CONV_BLKS + KTOT) {
        int k = b - CONV_BLKS;          // 0..767
        int dd = threadIdx.x;           // 0..255
        const float* W = (k < 256) ? Wn : ((k < 512) ? Wl : Wsc);
        Wt[(size_t)dd * KTOT + k] = f2bf(W[(k & 255) * DIM + dd]);
    } else {
        int e = (b - CONV_BLKS - KTOT) * 256 + threadIdx.x;
        if (e < N_EDGES) atomicAdd(&deg[dstv[e]], 1);
    }
}

// ---------------- K4a: per-block scan of deg ----------------
__global__ void scanA_kernel(const int* __restrict__ deg, int* __restrict__ excl_local,
                             int* __restrict__ block_sum) {
    __shared__ int sdata[SCAN_BLK];
    int t = threadIdx.x, i = blockIdx.x * SCAN_BLK + t;
    int v = (i < N_NODES) ? deg[i] : 0;
    sdata[t] = v;
    __syncthreads();
    for (int off = 1; off < SCAN_BLK; off <<= 1) {
        int u = (t >= off) ? sdata[t - off] : 0;
        __syncthreads();
        sdata[t] += u;
        __syncthreads();
    }
    if (i < N_NODES) excl_local[i] = sdata[t] - v;
    if (t == SCAN_BLK - 1) block_sum[blockIdx.x] = sdata[t];
}

// ---------------- K4b: scan 196 block sums (1 block) ----------------
__global__ void scanB_kernel(const int* __restrict__ block_sum, int* __restrict__ block_base,
                             int* __restrict__ offsets) {
    __shared__ int sdata[SCAN_NBLK];
    int t = threadIdx.x;
    int v = (t < SCAN_NBLK) ? block_sum[t] : 0;
    if (t < SCAN_NBLK) sdata[t] = v;
    __syncthreads();
    for (int off = 1; off < SCAN_NBLK; off <<= 1) {
        int u = (t >= off && t < SCAN_NBLK) ? sdata[t - off] : 0;
        __syncthreads();
        if (t < SCAN_NBLK) sdata[t] += u;
        __syncthreads();
    }
    if (t < SCAN_NBLK) block_base[t] = sdata[t] - v;
    if (t == SCAN_NBLK - 1) offsets[N_NODES] = sdata[t];
}

// ---------------- K4c: combine -> offsets, cursor ----------------
__global__ void scanC_kernel(const int* __restrict__ excl_local, const int* __restrict__ block_base,
                             int* __restrict__ offsets, int* __restrict__ cursor) {
    int i = blockIdx.x * SCAN_BLK + threadIdx.x;
    if (i < N_NODES) {
        int e = block_base[blockIdx.x] + excl_local[i];
        offsets[i] = e; cursor[i] = e;
    }
}

// ---------------- K5: scatter edges into CSR slots (packed src*500+et) ----------------
__global__ void scatter_kernel(const int* __restrict__ src, const int* __restrict__ dstv,
                               const int* __restrict__ et, int* __restrict__ cursor,
                               unsigned* __restrict__ esee) {
    int e = blockIdx.x * 256 + threadIdx.x;
    if (e >= N_EDGES) return;
    int d = dstv[e];
    int pos = atomicAdd(&cursor[d], 1);
    esee[pos] = (unsigned)src[e] * N_RELS + (unsigned)et[e];
}

// ---------------- K6: wave-per-node gather-reduce -> Xcat[:,0:256] ----------------
// 4-edge unroll for memory-level parallelism (latency-bound gather).
__global__ void agg_kernel(u16* __restrict__ Xcat, const u16* __restrict__ embb,
                           const float* __restrict__ norm, const int* __restrict__ offsets,
                           const unsigned* __restrict__ esee,
                           int* __restrict__ wl_count, int* __restrict__ wl) {
    int wave = (blockIdx.x * 256 + threadIdx.x) >> 6;
    int lane = threadIdx.x & 63;
    if (wave >= N_NODES) return;
    int n = wave;
    int s0 = offsets[n], s1 = offsets[n + 1];
    int c4 = lane * 4;
    float4 acc = make_float4(0.f, 0.f, 0.f, 0.f);
    int e = s0;
    for (; e + 3 < s1; e += 4) {
        unsigned v0 = esee[e], v1 = esee[e + 1], v2 = esee[e + 2], v3 = esee[e + 3];
        unsigned sa = v0 / N_RELS, ta = v0 - sa * N_RELS;
        unsigned sb = v1 / N_RELS, tb = v1 - sb * N_RELS;
        unsigned sc = v2 / N_RELS, tc = v2 - sc * N_RELS;
        unsigned sd = v3 / N_RELS, td = v3 - sd * N_RELS;
        ushort4 ha = *(const ushort4*)(Xcat + (size_t)sa * XW + 256 + c4);
        ushort4 ea = *(const ushort4*)(embb + (size_t)ta * DIM + c4);
        ushort4 hb = *(const ushort4*)(Xcat + (size_t)sb * XW + 256 + c4);
        ushort4 eb = *(const ushort4*)(embb + (size_t)tb * DIM + c4);
        ushort4 hc = *(const ushort4*)(Xcat + (size_t)sc * XW + 256 + c4);
        ushort4 ec = *(const ushort4*)(embb + (size_t)tc * DIM + c4);
        ushort4 hd = *(const ushort4*)(Xcat + (size_t)sd * XW + 256 + c4);
        ushort4 ed = *(const ushort4*)(embb + (size_t)td * DIM + c4);
        acc.x += (bf2f(ha.x) + bf2f(ea.x)) + (bf2f(hb.x) + bf2f(eb.x))
               + (bf2f(hc.x) + bf2f(ec.x)) + (bf2f(hd.x) + bf2f(ed.x));
        acc.y += (bf2f(ha.y) + bf2f(ea.y)) + (bf2f(hb.y) + bf2f(eb.y))
               + (bf2f(hc.y) + bf2f(ec.y)) + (bf2f(hd.y) + bf2f(ed.y));
        acc.z += (bf2f(ha.z) + bf2f(ea.z)) + (bf2f(hb.z) + bf2f(eb.z))
               + (bf2f(hc.z) + bf2f(ec.z)) + (bf2f(hd.z) + bf2f(ed.z));
        acc.w += (bf2f(ha.w) + bf2f(ea.w)) + (bf2f(hb.w) + bf2f(eb.w))
               + (bf2f(hc.w) + bf2f(ec.w)) + (bf2f(hd.w) + bf2f(ed.w));
    }
    for (; e < s1; e++) {
        unsigned v = esee[e];
        unsigned s = v / N_RELS;
        unsigned t = v - s * N_RELS;
        ushort4 hv = *(const ushort4*)(Xcat + (size_t)s * XW + 256 + c4);
        ushort4 ev = *(const ushort4*)(embb + (size_t)t * DIM + c4);
        acc.x += bf2f(hv.x) + bf2f(ev.x);
        acc.y += bf2f(hv.y) + bf2f(ev.y);
        acc.z += bf2f(hv.z) + bf2f(ev.z);
        acc.w += bf2f(hv.w) + bf2f(ev.w);
    }
    float nr = norm[n];
    u16 o[4] = { f2bf(acc.x * nr), f2bf(acc.y * nr), f2bf(acc.z * nr), f2bf(acc.w * nr) };
    *(ushort4*)(Xcat + (size_t)n * XW + c4) = *(const ushort4*)o;
    if (lane == 0 && s1 == s0) { int idx = atomicAdd(wl_count, 1); wl[idx] = n; }
}

// ---------------- K7: fused MFMA GEMM, counted-vmcnt, 8-wave high-occupancy ----------------
// Block: 512 thr = 8 waves (2M x 4N). Tile: 64 nodes x 256 cols, BK=64.
// Wave (wm, wc): rows [wm*32,+32), cols [wc*64,+64) -> acc 2x4 frags = 64 regs/thread
// (half of R2's 128) -> fits 4 waves/SIMD => 2 blocks/CU, 32 waves/CU (4x R2's TLP).
// All staging via global_load_lds (NO per-thread staging regs -> no spill channel, R3 lesson).
// Per thread per tile: exactly 5 gld16 (4 B + 1 A). Head waits vmcnt(5): tile kt landed,
// tile kt+1's 5 stay in flight across the raw s_barrier (T4).
// Swizzle: source chunk pre-XOR (lc8^lr), linear LDS dest, read chunk XOR (m16&7)<<3 —
// identical involution to R1-R3 (measured 0 bank conflicts).
// LDS: A dbuf 2x8KB @u16[0/4096], B dbuf 2x32KB @u16[8192/24576] = 80KB -> 2 blocks/CU.
__launch_bounds__(512, 4)
__global__ void gemm_kernel(const u16* __restrict__ Xcat, const u16* __restrict__ Wt,
                            const float* __restrict__ prev_h, const float* __restrict__ bias,
                            float* __restrict__ out) {
    __shared__ __align__(16) u16 lds[40960];   // 81920 B
    int tid  = threadIdx.x;
    int wave = tid >> 6, lane = tid & 63, q = lane >> 4, m16 = lane & 15;
    int wm = wave >> 2;              // M-group: rows [wm*32, +32)
    int wnn = (wave & 3) * 64;       // N-group: cols [wnn, +64)
    int m0 = blockIdx.x * 64;
    int lr = lane >> 3, lc8 = lane & 7;        // staging: row-in-issue / 16B-chunk
    int sc8 = (lc8 ^ lr) << 3;                 // pre-swizzled source chunk (u16 units)

    // A staging: wave stages rows [wave*8, +8)  (8 waves cover 64 rows)
    int arow = wave * 8 + lr;
    int ga = (m0 + arow < N_NODES) ? (m0 + arow) : (N_NODES - 1);
    const u16* sA = Xcat + (size_t)ga * XW + sc8;
    // B staging: wave stages Wt rows [wave*32, +32) in 4 issues of 8 rows
    const u16* sB = Wt + (size_t)(wave * 32 + lr) * KTOT + sc8;

    float4v acc1[2][4], acc2[2][4];
#pragma unroll
    for (int i = 0; i < 2; i++)
#pragma unroll
        for (int j = 0; j < 4; j++) { acc1[i][j] = (float4v)0.f; acc2[i][j] = (float4v)0.f; }

    auto stage = [&](int kt, int buf) {
#pragma unroll
        for (int j = 0; j < 4; j++)
            gld16(sB + (size_t)j * 8 * KTOT + kt * 64,
                  &lds[8192 + buf * 16384 + wave * 2048 + j * 512]);
        gld16(sA + kt * 64, &lds[buf * 4096 + wave * 512]);
    };

    // prologue: tiles 0 and 1 in flight (10 outstanding per thread)
    stage(0, 0);
    stage(1, 1);

    int sw = (m16 & 7) << 3;   // read-side swizzle (u16 units)

#pragma unroll
    for (int kt = 0; kt < 12; kt++) {
        int buf = kt & 1;
        // wait for MY tile-kt loads only; tile-kt+1's 5 stay in flight (T4)
        if (kt < 11) asm volatile("s_waitcnt vmcnt(5)" ::: "memory");
        else         asm volatile("s_waitcnt vmcnt(0)" ::: "memory");
        __builtin_amdgcn_sched_barrier(0);
        __builtin_amdgcn_s_barrier();          // every wave's tile-kt data now in LDS
        __builtin_amdgcn_sched_barrier(0);

#pragma unroll
        for (int kk = 0; kk < 2; kk++) {
            int ck = (kk * 32 + q * 8) ^ sw;
            short8v af[2], bfr[4];
#pragma unroll
            for (int mi = 0; mi < 2; mi++)
                af[mi] = *(const short8v*)(&lds[buf * 4096 + (wm * 32 + mi * 16 + m16) * 64 + ck]);
#pragma unroll
            for (int ni = 0; ni < 4; ni++)
                bfr[ni] = *(const short8v*)(&lds[8192 + buf * 16384 + (wnn + ni * 16 + m16) * 64 + ck]);
            if (kt < 8) {
#pragma unroll
                for (int mi = 0; mi < 2; mi++)
#pragma unroll
                    for (int ni = 0; ni < 4; ni++)
                        acc1[mi][ni] = __builtin_amdgcn_mfma_f32_16x16x32_bf16(
                            af[mi], bfr[ni], acc1[mi][ni], 0, 0, 0);
            } else {
#pragma unroll
                for (int mi = 0; mi < 2; mi++)
#pragma unroll
                    for (int ni = 0; ni < 4; ni++)
                        acc2[mi][ni] = __builtin_amdgcn_mfma_f32_16x16x32_bf16(
                            af[mi], bfr[ni], acc2[mi][ni], 0, 0, 0);
            }
        }

        __builtin_amdgcn_sched_barrier(0);
        __builtin_amdgcn_s_barrier();          // all waves done READING buf -> safe to restage
        __builtin_amdgcn_sched_barrier(0);
        if (kt + 2 < 12) stage(kt + 2, buf);
    }

    // epilogue: C/D layout col=lane&15, row=q*4+reg  [measured m89]
#pragma unroll
    for (int mi = 0; mi < 2; mi++) {
#pragma unroll
        for (int ni = 0; ni < 4; ni++) {
            int d = wnn + ni * 16 + m16;
            float b = bias[d];
#pragma unroll
            for (int r = 0; r < 4; r++) {
                int node = m0 + wm * 32 + mi * 16 + q * 4 + r;
                if (node < N_NODES) {
                    float S  = acc2[mi][ni][r] + b;
                    float sg = 1.f / (1.f + __expf(-S));
                    float ph = prev_h[(size_t)node * DIM + d];
                    float v  = sg * acc1[mi][ni][r] + (1.f - sg) * ph;
                    out[(size_t)node * DIM + d] = fmaxf(v, 0.f);
                }
            }
        }
    }
}

// ---------------- K8: fixup for in_deg==0 nodes (evolve_loop_weight path, exact fp32) --------
__global__ void fixup_kernel(const float* __restrict__ h, const float* __restrict__ prev_h,
                             const float* __restrict__ We, const float* __restrict__ Wsc,
                             const float* __restrict__ bias, const int* __restrict__ wl_count,
                             const int* __restrict__ wl, float* __restrict__ out) {
    __shared__ float ph[DIM], hh[DIM];
    int d = threadIdx.x;
    int cnt = *wl_count;
    for (int i = blockIdx.x; i < cnt; i += gridDim.x) {
        int n = wl[i];
        ph[d] = prev_h[(size_t)n * DIM + d];
        hh[d] = h[(size_t)n * DIM + d];
        __syncthreads();
        float s = 0.f, l = 0.f;
        for (int k = 0; k < DIM; k++) {
            s += ph[k] * Wsc[k * DIM + d];
            l += hh[k] * We[k * DIM + d];
        }
        float sg = 1.f / (1.f + __expf(-(s + bias[d])));
        float v = sg * l + (1.f - sg) * ph[d];
        out[(size_t)n * DIM + d] = fmaxf(v, 0.f);
        __syncthreads();
    }
}

extern "C" void kernel_launch(void* const* d_in, const int* in_sizes, int n_in,
                              void* d_out, int out_size, void* d_ws, size_t ws_size,
                              hipStream_t stream) {
    const float* h      = (const float*)d_in[0];
    const float* prev_h = (const float*)d_in[1];
    const float* emb    = (const float*)d_in[2];
    const float* norm   = (const float*)d_in[3];
    const float* Wn     = (const float*)d_in[4];
    const float* Wl     = (const float*)d_in[5];
    const float* We     = (const float*)d_in[6];
    const float* Wsc    = (const float*)d_in[7];
    const float* bias   = (const float*)d_in[8];
    const int*   src    = (const int*)d_in[9];
    const int*   dstv   = (const int*)d_in[10];
    const int*   et     = (const int*)d_in[11];
    float* out = (float*)d_out;

    char* ws = (char*)d_ws;
    size_t off = 0;
    auto alloc = [&](size_t bytes) -> char* {
        char* p = ws + off; off += (bytes + 255) & ~(size_t)255; return p;
    };
    u16* Xcat    = (u16*)alloc((size_t)N_NODES * XW * 2);   // [agg | h | prev] bf16
    u16* embb    = (u16*)alloc((size_t)N_RELS * DIM * 2);
    u16* Wt      = (u16*)alloc((size_t)DIM * KTOT * 2);
    int* deg     = (int*)alloc((size_t)N_NODES * 4);
    int* wlcnt   = (int*)alloc(16);
    int* wl      = (int*)alloc((size_t)N_NODES * 4);
    int* offsets = (int*)alloc((size_t)(N_NODES + 1) * 4);
    int* cursor  = (int*)alloc((size_t)N_NODES * 4);
    unsigned* esee = (unsigned*)alloc((size_t)N_EDGES * 4);
    int* excl    = (int*)alloc((size_t)N_NODES * 4);
    int* bsum    = (int*)alloc((size_t)SCAN_NBLK * 4);
    int* bbase   = (int*)alloc((size_t)SCAN_NBLK * 4);

    hipMemsetAsync(deg, 0, (size_t)N_NODES * 4, stream);
    hipMemsetAsync(wlcnt, 0, 4, stream);

    prep_kernel<<<CONV_BLKS + KTOT + HIST_BLKS, 256, 0, stream>>>(
        h, prev_h, emb, Wn, Wl, Wsc, dstv, Xcat, embb, Wt, deg);
    scanA_kernel<<<SCAN_NBLK, SCAN_BLK, 0, stream>>>(deg, excl, bsum);
    scanB_kernel<<<1, SCAN_BLK, 0, stream>>>(bsum, bbase, offsets);
    scanC_kernel<<<SCAN_NBLK, SCAN_BLK, 0, stream>>>(excl, bbase, offsets, cursor);
    scatter_kernel<<<(N_EDGES + 255) / 256, 256, 0, stream>>>(src, dstv, et, cursor, esee);
    agg_kernel<<<(N_NODES + 3) / 4, 256, 0, stream>>>(Xcat, embb, norm, offsets, esee, wlcnt, wl);
    gemm_kernel<<<(N_NODES + 63) / 64, 512, 0, stream>>>(Xcat, Wt, prev_h, bias, out);
    fixup_kernel<<<256, 256, 0, stream>>>(h, prev_h, We, Wsc, bias, wlcnt, wl, out);
}